// Round 7
// baseline (235.064 us; speedup 1.0000x reference)
//
#include <hip/hip_runtime.h>
#include <math.h>

// Problem constants (fixed by setup_inputs)
#define NQRY 8192   // queries
#define DIM  256    // d
#define MS   4608   // memory slots m
#define NQE  16384  // Nq embeddings
#define NBLK 8      // m // (C-1) partitions -> 8 blocks of 576
#define PRROWS 576

typedef __attribute__((ext_vector_type(8))) short bf16x8;
typedef __attribute__((ext_vector_type(4))) float f32x4;
typedef __attribute__((ext_vector_type(16))) float f32x16;

// ---- d_out scratch layout (float offsets). All scratch is dead before
// k_read_mfma overwrites the entire output buffer. (R3/R6-proven layout) ----
// q f32      [8192][256]   @ 0
// qh bf16    [8192][256]   @ 2,097,152
// ql bf16    [8192][256]   @ 3,145,728
// kh bf16    [4608][256]   @ 4,194,304
// kl bf16    [4608][256]   @ 4,784,128
// qu f32     [4608][256]   @ 5,373,952
// rowbest u64[8192]        @ 6,553,600
// colmax u32 [4608]        @ 6,569,984
// memr f32   [4608][256]   @ 6,574,592   (ends 7,754,240 < 67,108,864)
// ---- d_ws layout (bytes): ebT bf16 [2][16384][256] @ 0 (16 MB);
//      Gb bf16 [8][256][256] @ 16,777,216 (1 MB); sc f32[4] @ 17,825,792.

// Order-preserving float<->uint mapping for atomicMax on floats
__device__ __forceinline__ unsigned ordf(float f) {
  unsigned u = __float_as_uint(f);
  return (u & 0x80000000u) ? ~u : (u | 0x80000000u);
}
__device__ __forceinline__ float unordf(unsigned u) {
  unsigned b = (u & 0x80000000u) ? (u & 0x7FFFFFFFu) : ~u;
  return __uint_as_float(b);
}
// round-to-nearest-even f32 -> bf16 bits
__device__ __forceinline__ unsigned short bf16rn(float x) {
  unsigned u = __float_as_uint(x);
  unsigned r = u + 0x7FFFu + ((u >> 16) & 1u);
  return (unsigned short)(r >> 16);
}
// split: x = hi(bf16, trunc) + lo(bf16, RN); residual <= 2^-17 |x|
__device__ __forceinline__ void splitbf(float x, unsigned short& h, unsigned short& lo) {
  unsigned u = __float_as_uint(x);
  h = (unsigned short)(u >> 16);
  float hf = __uint_as_float(u & 0xFFFF0000u);
  lo = bf16rn(x - hf);
}

// K_prep: fused prep pipeline, role by blockIdx range:
// [0,8192)      qnorm block i
// [8192,12800)  ksplit
// [12800,16896) embt (decode 512 x 4 x 2)
// [16896,18069) zero qu+rowbest+colmax
// 18069         scalars
#define PREP_NBLK 18070
#define ZERO_N4   300160
__global__ __launch_bounds__(256) void k_prep(
    const float* __restrict__ query, float* __restrict__ q,
    unsigned short* __restrict__ qh, unsigned short* __restrict__ ql,
    const float* __restrict__ keys,
    unsigned short* __restrict__ kh, unsigned short* __restrict__ kl,
    const float* __restrict__ embS, const float* __restrict__ embT,
    unsigned short* __restrict__ ebT,
    float4* __restrict__ zp,
    const int* __restrict__ labels, const float* __restrict__ cc,
    float* __restrict__ sc) {
  __shared__ float tile[64][33];
  int b = blockIdx.x, t = threadIdx.x;
  if (b < 8192) {
    // qnorm
    size_t idx = (size_t)b * DIM + t;
    float x = query[idx];
    float v = x * x;
    #pragma unroll
    for (int o = 32; o; o >>= 1) v += __shfl_down(v, o);
    float* s = &tile[0][0];
    if ((t & 63) == 0) s[t >> 6] = v;
    __syncthreads();
    float ss = (s[0] + s[1]) + (s[2] + s[3]);
    float qq = x / fmaxf(sqrtf(ss), 1e-12f);
    q[idx] = qq;
    unsigned short h, lo;
    splitbf(qq, h, lo);
    qh[idx] = h; ql[idx] = lo;
  } else if (b < 12800) {
    // ksplit
    size_t idx = (size_t)(b - 8192) * 256 + t;
    unsigned short h, lo;
    splitbf(keys[idx], h, lo);
    kh[idx] = h; kl[idx] = lo;
  } else if (b < 16896) {
    // embt: transpose+convert emb [k][n] f32 -> ebT [n][k] bf16
    int bb = b - 12800;
    int x = bb & 511, y = (bb >> 9) & 3, z = bb >> 11;
    const float* emb = z ? embT : embS;
    int n0 = x * 32, k0 = y * 64;
    int kl2 = t >> 5, nl = t & 31;
    #pragma unroll
    for (int i = 0; i < 8; i++)
      tile[kl2 * 8 + i][nl] = emb[(size_t)(k0 + kl2 * 8 + i) * NQE + n0 + nl];
    __syncthreads();
    int nl2 = t >> 3, kq = (t & 7) * 8;
    bf16x8 hv;
    #pragma unroll
    for (int j = 0; j < 8; j++) hv[j] = (short)bf16rn(tile[kq + j][nl2]);
    *(bf16x8*)(ebT + (size_t)z * NQE * DIM + (size_t)(n0 + nl2) * DIM + k0 + kq) = hv;
  } else if (b < 18069) {
    // zero
    int i = (b - 16896) * 256 + t;
    if (i < ZERO_N4) zp[i] = float4{0.f, 0.f, 0.f, 0.f};
  } else {
    // scalars (wave 0 only)
    if (t < 64) {
      int l = (t < 16) ? labels[t] : (int)0x80000000;
      int mx = l;
      #pragma unroll
      for (int o = 32; o; o >>= 1) mx = max(mx, __shfl_down(mx, o));
      mx = __shfl(mx, 0);
      int cnt = (t < 16 && l == mx) ? 1 : 0;
      #pragma unroll
      for (int o = 32; o; o >>= 1) cnt += __shfl_down(cnt, o);
      unsigned amv = (t < 16) ? (1u << l) : 0u;
      #pragma unroll
      for (int o = 32; o; o >>= 1) amv |= __shfl_down(amv, o);
      if (t == 0) {
        sc[0] = __int_as_float(mx);
        sc[1] = (float)cnt;
        sc[2] = cc[mx];
        sc[3] = __uint_as_float(amv);
      }
    }
  }
}

// K4: score GEMM, split-bf16 3-pass, BK=32 hi/lo-interleaved 128B LDS rows
// (R6-proven staging + swizzle), MFMA shape 32x32x16 (fewer issue cycles,
// fewer index ops; A/B layout: row=lane&31, k=(lane>>5)*8+e; C/D layout:
// col=lane&31, row=(reg&3)+8*(reg>>2)+4*(lane>>5) [m74/m101-verified]).
// Same 2-barrier replay-stable template. Fused argmax/colmax epilogue.
__global__ __launch_bounds__(256) void k_scoremax(
    const unsigned short* __restrict__ qh, const unsigned short* __restrict__ ql,
    const unsigned short* __restrict__ kh, const unsigned short* __restrict__ kl,
    unsigned long long* __restrict__ rowbest, unsigned* __restrict__ colmax) {
  __shared__ __align__(16) char smem[32768];
  char* sA = smem;
  char* sB = smem + 16384;
  int tid = threadIdx.x;
  int n0 = blockIdx.x * 128, m0 = blockIdx.y * 128;   // n: slots, m: queries
  int w = tid >> 6, lane = tid & 63;
  int wm = w >> 1, wn = w & 1;
  int l31 = lane & 31, hi5 = lane >> 5;
  int srow = tid >> 3, sc8 = tid & 7;   // staging: row-slot 0..31, chunk 0..7
  f32x16 acc[2][2] = {};
  for (int kk = 0; kk < 8; kk++) {
    __syncthreads();
    #pragma unroll
    for (int t = 0; t < 8; t++) {
      int row = (t & 3) * 32 + srow;
      const unsigned short* hsrc = (t < 4) ? qh : kh;
      const unsigned short* lsrc = (t < 4) ? ql : kl;
      int base = (t < 4) ? m0 : n0;
      const unsigned short* src =
          ((sc8 < 4) ? hsrc : lsrc) + (size_t)(base + row) * DIM + kk * 32 + (sc8 & 3) * 8;
      char* dst = ((t < 4) ? sA : sB) + row * 128 + ((sc8 ^ (row & 7)) << 4);
      *(bf16x8*)dst = *(const bf16x8*)src;
    }
    __syncthreads();
    // A fragments: row = wm*64 + fm*32 + l31; k-chunk = h*2 + hi5 (hi), +4 (lo)
    bf16x8 ah[2][2], al[2][2];
    #pragma unroll
    for (int fm = 0; fm < 2; fm++) {
      int ra = wm * 64 + fm * 32 + l31;
      #pragma unroll
      for (int h = 0; h < 2; h++) {
        int ch = h * 2 + hi5;
        ah[fm][h] = *(const bf16x8*)(sA + ra * 128 + ((ch ^ (ra & 7)) << 4));
        al[fm][h] = *(const bf16x8*)(sA + ra * 128 + (((ch + 4) ^ (ra & 7)) << 4));
      }
    }
    #pragma unroll
    for (int fn = 0; fn < 2; fn++) {
      int rb = wn * 64 + fn * 32 + l31;
      bf16x8 bh[2], bl[2];
      #pragma unroll
      for (int h = 0; h < 2; h++) {
        int ch = h * 2 + hi5;
        bh[h] = *(const bf16x8*)(sB + rb * 128 + ((ch ^ (rb & 7)) << 4));
        bl[h] = *(const bf16x8*)(sB + rb * 128 + (((ch + 4) ^ (rb & 7)) << 4));
      }
      #pragma unroll
      for (int fm = 0; fm < 2; fm++)
        #pragma unroll
        for (int h = 0; h < 2; h++) {
          acc[fm][fn] = __builtin_amdgcn_mfma_f32_32x32x16_bf16(ah[fm][h], bh[h], acc[fm][fn], 0, 0, 0);
          acc[fm][fn] = __builtin_amdgcn_mfma_f32_32x32x16_bf16(ah[fm][h], bl[h], acc[fm][fn], 0, 0, 0);
          acc[fm][fn] = __builtin_amdgcn_mfma_f32_32x32x16_bf16(al[fm][h], bh[h], acc[fm][fn], 0, 0, 0);
        }
    }
  }
  // epilogue: row argmax (packed u64) + column max, 32x32 C/D layout
  #pragma unroll
  for (int fm = 0; fm < 2; fm++) {
    #pragma unroll
    for (int reg = 0; reg < 16; reg++) {
      unsigned long long p = 0ull;
      #pragma unroll
      for (int fn = 0; fn < 2; fn++) {
        float v = acc[fm][fn][reg];
        unsigned ng = (unsigned)(n0 + wn * 64 + fn * 32 + l31);
        unsigned long long cand =
            ((unsigned long long)ordf(v) << 32) | (unsigned long long)(0xFFFFFFFFu - ng);
        if (cand > p) p = cand;
      }
      #pragma unroll
      for (int o = 1; o < 32; o <<= 1) {
        unsigned long long t2 = __shfl_xor(p, o);
        if (t2 > p) p = t2;
      }
      if (l31 == 0) {
        int rl = (reg & 3) + 8 * (reg >> 2) + 4 * hi5;
        atomicMax(rowbest + (m0 + wm * 64 + fm * 32 + rl), p);
      }
    }
  }
  #pragma unroll
  for (int fn = 0; fn < 2; fn++) {
    float v = -3.4e38f;
    #pragma unroll
    for (int fm = 0; fm < 2; fm++)
      #pragma unroll
      for (int reg = 0; reg < 16; reg++) v = fmaxf(v, acc[fm][fn][reg]);
    v = fmaxf(v, __shfl_xor(v, 32));
    if (hi5 == 0) atomicMax(colmax + (n0 + wn * 64 + fn * 32 + l31), ordf(v));
  }
}

// K5: per-query scatter using rowbest/colmax only (no S).
__global__ __launch_bounds__(256) void k_rowscatter(
    const unsigned long long* __restrict__ rowbest, const unsigned* __restrict__ colmax,
    const float* __restrict__ q, float* __restrict__ qu) {
  int i = blockIdx.x, t = threadIdx.x;
  unsigned long long p = rowbest[i];
  int g = (int)(0xFFFFFFFFu - (unsigned)(p & 0xFFFFFFFFull));
  float sv = unordf((unsigned)(p >> 32));
  float w = expf(sv - unordf(colmax[g]));
  atomicAdd(qu + (size_t)g * DIM + t, w * q[(size_t)i * DIM + t]);
}

// K6: mem = l2norm((temp*keys + qu*active) / temp2)
__global__ __launch_bounds__(256) void k_mem(const float* __restrict__ keys,
                                             const float* __restrict__ qu,
                                             const float* __restrict__ sc,
                                             float* __restrict__ memr) {
  int j = blockIdx.x, t = threadIdx.x;
  int last = __float_as_int(sc[0]);
  float count = sc[1], ccl = sc[2];
  unsigned am = __float_as_uint(sc[3]);
  int cls = j >> 9;  // part = 512
  bool inp = (cls == last);
  float temp = inp ? ccl : 1.0f;
  float quv = ((am >> cls) & 1u) ? qu[(size_t)j * DIM + t] : 0.0f;
  float u = temp * keys[(size_t)j * DIM + t] + quv;
  float temp2 = temp + (inp ? count : 0.0f);
  float v = u / temp2;
  float vv = v * v;
  #pragma unroll
  for (int o = 32; o; o >>= 1) vv += __shfl_down(vv, o);
  __shared__ float s[4];
  if ((t & 63) == 0) s[t >> 6] = vv;
  __syncthreads();
  float ss = (s[0] + s[1]) + (s[2] + s[3]);
  memr[(size_t)j * DIM + t] = v / fmaxf(sqrtf(ss), 1e-12f);
}

// K7: G_b = B_b^T B_b (f32 vector compute), emit single bf16 (RN).
__global__ __launch_bounds__(256) void k_gram(const float* __restrict__ memr,
                                              unsigned short* __restrict__ Gb) {
  __shared__ float As[16][64];
  __shared__ float Bs[16][64];
  int b = blockIdx.z;
  int kxc = blockIdx.x * 64;
  int kyr = blockIdx.y * 64;
  const float* Ab = memr + (size_t)b * PRROWS * DIM;
  int tid = threadIdx.x, tx = tid & 15, ty = tid >> 4;
  int lp = tid >> 4;
  int lk = (tid & 15) * 4;
  float acc[4][4] = {};
  for (int p0 = 0; p0 < PRROWS; p0 += 16) {
    float4 av = *(const float4*)(Ab + (size_t)(p0 + lp) * DIM + kyr + lk);
    float4 bv = *(const float4*)(Ab + (size_t)(p0 + lp) * DIM + kxc + lk);
    __syncthreads();
    *(float4*)&As[lp][lk] = av;
    *(float4*)&Bs[lp][lk] = bv;
    __syncthreads();
    #pragma unroll
    for (int p = 0; p < 16; p++) {
      float a[4], c[4];
      *(float4*)&a[0] = *(const float4*)&As[p][ty * 4];
      *(float4*)&c[0] = *(const float4*)&Bs[p][tx * 4];
      #pragma unroll
      for (int r = 0; r < 4; r++)
        #pragma unroll
        for (int s2 = 0; s2 < 4; s2++)
          acc[r][s2] = fmaf(a[r], c[s2], acc[r][s2]);
    }
  }
  #pragma unroll
  for (int r = 0; r < 4; r++)
    #pragma unroll
    for (int s2 = 0; s2 < 4; s2++)
      Gb[(size_t)b * DIM * DIM + (size_t)(kyr + ty * 4 + r) * DIM + kxc + tx * 4 + s2] =
          bf16rn(acc[r][s2]);
}

// K8: out[eb][n][d] = ebT_e[n,:] @ G_b, 1-pass bf16 MFMA, reg-staged LDS
// (verbatim round-3/6 kernel: validated + replay-stable).
__global__ __launch_bounds__(256) void k_read_mfma(
    const unsigned short* __restrict__ ebT, const unsigned short* __restrict__ Gb,
    float* __restrict__ out) {
  __shared__ __align__(16) char smem[32768];
  char* sA = smem;
  char* sB = smem + 16384;
  int tid = threadIdx.x;
  int eb = blockIdx.z;
  const unsigned short* ea = ebT + (size_t)(eb >> 3) * NQE * DIM;
  const unsigned short* gb = Gb + (size_t)(eb & 7) * DIM * DIM;
  int n0 = blockIdx.x * 128, d0 = blockIdx.y * 128;
  int w = tid >> 6, l = tid & 63;
  int wm = w >> 1, wn = w & 1;
  int lr = l >> 4, lc = l & 15;
  f32x4 acc[4][4] = {};
  for (int kk = 0; kk < 4; kk++) {
    __syncthreads();
    #pragma unroll
    for (int t = 0; t < 4; t++) {
      int c = t * 256 + tid;            // 16B chunk id, 0..1023
      int row = c >> 3, cc = c & 7;
      int ldsb = row * 128 + ((cc * 16) ^ ((row & 7) << 4));
      size_t gA = (size_t)(n0 + row) * DIM + kk * 64 + cc * 8;
      size_t gB = (size_t)(d0 + row) * DIM + kk * 64 + cc * 8;
      *(bf16x8*)(sA + ldsb) = *(const bf16x8*)(ea + gA);
      *(bf16x8*)(sB + ldsb) = *(const bf16x8*)(gb + gB);
    }
    __syncthreads();
    #pragma unroll
    for (int st = 0; st < 2; st++) {
      bf16x8 af[4], bf[4];
      #pragma unroll
      for (int f = 0; f < 4; f++) {
        int ra = wm * 64 + f * 16 + lc;
        int ka = (st * 64 + lr * 16) ^ ((ra & 7) << 4);
        af[f] = *(const bf16x8*)(sA + ra * 128 + ka);
        int rb = wn * 64 + f * 16 + lc;
        int kb = (st * 64 + lr * 16) ^ ((rb & 7) << 4);
        bf[f] = *(const bf16x8*)(sB + rb * 128 + kb);
      }
      #pragma unroll
      for (int fm = 0; fm < 4; fm++)
        #pragma unroll
        for (int fn = 0; fn < 4; fn++)
          acc[fm][fn] = __builtin_amdgcn_mfma_f32_16x16x32_bf16(af[fm], bf[fn], acc[fm][fn], 0, 0, 0);
    }
  }
  size_t base = (size_t)eb * NQE * DIM;
  #pragma unroll
  for (int fm = 0; fm < 4; fm++)
    #pragma unroll
    for (int rg = 0; rg < 4; rg++) {
      int n = n0 + wm * 64 + fm * 16 + lr * 4 + rg;
      float* op = out + base + (size_t)n * DIM + d0 + wn * 64 + lc;
      #pragma unroll
      for (int fn = 0; fn < 4; fn++) op[fn * 16] = acc[fm][fn][rg];
    }
}

extern "C" void kernel_launch(void* const* d_in, const int* in_sizes, int n_in,
                              void* d_out, int out_size, void* d_ws, size_t ws_size,
                              hipStream_t stream) {
  const float* query  = (const float*)d_in[0];
  const float* embS   = (const float*)d_in[1];
  const float* embT   = (const float*)d_in[2];
  const float* keys   = (const float*)d_in[3];
  const float* cc     = (const float*)d_in[4];
  const int*   labels = (const int*)d_in[5];
  float* out = (float*)d_out;

  float* q                     = out;
  unsigned short* qh           = (unsigned short*)(out + 2097152);
  unsigned short* ql           = (unsigned short*)(out + 3145728);
  unsigned short* kh           = (unsigned short*)(out + 4194304);
  unsigned short* kl           = (unsigned short*)(out + 4784128);
  float* qu                    = out + 5373952;
  unsigned long long* rowbest  = (unsigned long long*)(out + 6553600);
  unsigned* colmax             = (unsigned*)(out + 6569984);
  float* memr                  = out + 6574592;

  unsigned short* ebT = (unsigned short*)d_ws;                         // 16 MB
  unsigned short* Gb  = (unsigned short*)((char*)d_ws + 16777216);     // 1 MB
  float* sc           = (float*)((char*)d_ws + 17825792);              // 16 B

  k_prep<<<PREP_NBLK, 256, 0, stream>>>(query, q, qh, ql, keys, kh, kl,
                                        embS, embT, ebT, (float4*)qu,
                                        labels, cc, sc);
  k_scoremax<<<dim3(MS / 128, NQRY / 128), 256, 0, stream>>>(qh, ql, kh, kl, rowbest, colmax);
  k_rowscatter<<<NQRY, 256, 0, stream>>>(rowbest, colmax, q, qu);
  k_mem<<<MS, 256, 0, stream>>>(keys, qu, sc, memr);
  k_gram<<<dim3(4, 4, NBLK), 256, 0, stream>>>(memr, Gb);
  k_read_mfma<<<dim3(NQE / 128, DIM / 128, 2 * NBLK), 256, 0, stream>>>(ebT, Gb, out);
}

// Round 8
// 214.381 us; speedup vs baseline: 1.0965x; 1.0965x over previous
//
#include <hip/hip_runtime.h>
#include <math.h>

// Problem constants (fixed by setup_inputs)
#define NQRY 8192   // queries
#define DIM  256    // d
#define MS   4608   // memory slots m
#define NQE  16384  // Nq embeddings
#define NBLK 8      // m // (C-1) partitions -> 8 blocks of 576
#define PRROWS 576

typedef __attribute__((ext_vector_type(8))) short bf16x8;
typedef __attribute__((ext_vector_type(4))) float f32x4;

// ---- d_out scratch layout (float offsets). All scratch is dead before
// k_read_mfma overwrites the entire output buffer. (R3/R6-proven layout) ----
// q f32      [8192][256]   @ 0
// qh bf16    [8192][256]   @ 2,097,152
// ql bf16    [8192][256]   @ 3,145,728
// kh bf16    [4608][256]   @ 4,194,304
// kl bf16    [4608][256]   @ 4,784,128
// qu f32     [4608][256]   @ 5,373,952
// rowbest u64[8192]        @ 6,553,600
// colmax u32 [4608]        @ 6,569,984
// memr f32   [4608][256]   @ 6,574,592   (ends 7,754,240 < 67,108,864)
// ---- d_ws layout (bytes): ebT bf16 [2][16384][256] @ 0 (16 MB);
//      Gb bf16 [8][256][256] @ 16,777,216 (1 MB); sc f32[4] @ 17,825,792.

// Order-preserving float<->uint mapping for atomicMax on floats
__device__ __forceinline__ unsigned ordf(float f) {
  unsigned u = __float_as_uint(f);
  return (u & 0x80000000u) ? ~u : (u | 0x80000000u);
}
__device__ __forceinline__ float unordf(unsigned u) {
  unsigned b = (u & 0x80000000u) ? (u & 0x7FFFFFFFu) : ~u;
  return __uint_as_float(b);
}
// round-to-nearest-even f32 -> bf16 bits
__device__ __forceinline__ unsigned short bf16rn(float x) {
  unsigned u = __float_as_uint(x);
  unsigned r = u + 0x7FFFu + ((u >> 16) & 1u);
  return (unsigned short)(r >> 16);
}
// split: x = hi(bf16, trunc) + lo(bf16, RN); residual <= 2^-17 |x|
__device__ __forceinline__ void splitbf(float x, unsigned short& h, unsigned short& lo) {
  unsigned u = __float_as_uint(x);
  h = (unsigned short)(u >> 16);
  float hf = __uint_as_float(u & 0xFFFF0000u);
  lo = bf16rn(x - hf);
}

// K_prep: fused prep pipeline, role by blockIdx range (R7-proven):
// [0,8192) qnorm | [8192,12800) ksplit | [12800,16896) embt
// [16896,18069) zero qu+rowbest+colmax | 18069 scalars
#define PREP_NBLK 18070
#define ZERO_N4   300160
__global__ __launch_bounds__(256) void k_prep(
    const float* __restrict__ query, float* __restrict__ q,
    unsigned short* __restrict__ qh, unsigned short* __restrict__ ql,
    const float* __restrict__ keys,
    unsigned short* __restrict__ kh, unsigned short* __restrict__ kl,
    const float* __restrict__ embS, const float* __restrict__ embT,
    unsigned short* __restrict__ ebT,
    float4* __restrict__ zp,
    const int* __restrict__ labels, const float* __restrict__ cc,
    float* __restrict__ sc) {
  __shared__ float tile[64][33];
  int b = blockIdx.x, t = threadIdx.x;
  if (b < 8192) {
    // qnorm
    size_t idx = (size_t)b * DIM + t;
    float x = query[idx];
    float v = x * x;
    #pragma unroll
    for (int o = 32; o; o >>= 1) v += __shfl_down(v, o);
    float* s = &tile[0][0];
    if ((t & 63) == 0) s[t >> 6] = v;
    __syncthreads();
    float ss = (s[0] + s[1]) + (s[2] + s[3]);
    float qq = x / fmaxf(sqrtf(ss), 1e-12f);
    q[idx] = qq;
    unsigned short h, lo;
    splitbf(qq, h, lo);
    qh[idx] = h; ql[idx] = lo;
  } else if (b < 12800) {
    // ksplit
    size_t idx = (size_t)(b - 8192) * 256 + t;
    unsigned short h, lo;
    splitbf(keys[idx], h, lo);
    kh[idx] = h; kl[idx] = lo;
  } else if (b < 16896) {
    // embt: transpose+convert emb [k][n] f32 -> ebT [n][k] bf16
    int bb = b - 12800;
    int x = bb & 511, y = (bb >> 9) & 3, z = bb >> 11;
    const float* emb = z ? embT : embS;
    int n0 = x * 32, k0 = y * 64;
    int kl2 = t >> 5, nl = t & 31;
    #pragma unroll
    for (int i = 0; i < 8; i++)
      tile[kl2 * 8 + i][nl] = emb[(size_t)(k0 + kl2 * 8 + i) * NQE + n0 + nl];
    __syncthreads();
    int nl2 = t >> 3, kq = (t & 7) * 8;
    bf16x8 hv;
    #pragma unroll
    for (int j = 0; j < 8; j++) hv[j] = (short)bf16rn(tile[kq + j][nl2]);
    *(bf16x8*)(ebT + (size_t)z * NQE * DIM + (size_t)(n0 + nl2) * DIM + k0 + kq) = hv;
  } else if (b < 18069) {
    // zero
    int i = (b - 16896) * 256 + t;
    if (i < ZERO_N4) zp[i] = float4{0.f, 0.f, 0.f, 0.f};
  } else {
    // scalars (wave 0 only)
    if (t < 64) {
      int l = (t < 16) ? labels[t] : (int)0x80000000;
      int mx = l;
      #pragma unroll
      for (int o = 32; o; o >>= 1) mx = max(mx, __shfl_down(mx, o));
      mx = __shfl(mx, 0);
      int cnt = (t < 16 && l == mx) ? 1 : 0;
      #pragma unroll
      for (int o = 32; o; o >>= 1) cnt += __shfl_down(cnt, o);
      unsigned amv = (t < 16) ? (1u << l) : 0u;
      #pragma unroll
      for (int o = 32; o; o >>= 1) amv |= __shfl_down(amv, o);
      if (t == 0) {
        sc[0] = __int_as_float(mx);
        sc[1] = (float)cnt;
        sc[2] = cc[mx];
        sc[3] = __uint_as_float(amv);
      }
    }
  }
}

// K4: score GEMM — R6-proven kernel (16x16x32 MFMA, BK=32 hi/lo-interleaved
// 128B LDS rows, XOR-(row&7) swizzle, 32KB LDS, 2-barrier template) plus
// T14 async-STAGE split: next K-tile's 8 global loads issue BEFORE the MFMA
// cluster (compute ~425 cyc covers L2 ~200 cyc latency); ds_write lands
// after the next barrier. Plain loads/stores only — no async builtins.
__global__ __launch_bounds__(256) void k_scoremax(
    const unsigned short* __restrict__ qh, const unsigned short* __restrict__ ql,
    const unsigned short* __restrict__ kh, const unsigned short* __restrict__ kl,
    unsigned long long* __restrict__ rowbest, unsigned* __restrict__ colmax) {
  __shared__ __align__(16) char smem[32768];
  char* sA = smem;
  char* sB = smem + 16384;
  int tid = threadIdx.x;
  int n0 = blockIdx.x * 128, m0 = blockIdx.y * 128;   // n: slots, m: queries
  int w = tid >> 6, lane = tid & 63;
  int wm = w >> 1, wn = w & 1;
  int lr = lane >> 4, lc = lane & 15;
  int srow = tid >> 3, sc8 = tid & 7;   // staging: row-slot 0..31, chunk 0..7
  // per-role staging source base (row, hi/lo select fixed per t)
  bf16x8 pf[8];
  #pragma unroll
  for (int t = 0; t < 8; t++) {
    int row = (t & 3) * 32 + srow;
    const unsigned short* hsrc = (t < 4) ? qh : kh;
    const unsigned short* lsrc = (t < 4) ? ql : kl;
    int base = (t < 4) ? m0 : n0;
    pf[t] = *(const bf16x8*)(((sc8 < 4) ? hsrc : lsrc) +
                             (size_t)(base + row) * DIM + (sc8 & 3) * 8);
  }
  f32x4 acc[4][4] = {};
  for (int kk = 0; kk < 8; kk++) {
    __syncthreads();   // previous compute done reading LDS
    #pragma unroll
    for (int t = 0; t < 8; t++) {
      int row = (t & 3) * 32 + srow;
      char* dst = ((t < 4) ? sA : sB) + row * 128 + ((sc8 ^ (row & 7)) << 4);
      *(bf16x8*)dst = pf[t];
    }
    __syncthreads();
    if (kk < 7) {      // prefetch next K-tile (wave-uniform branch)
      #pragma unroll
      for (int t = 0; t < 8; t++) {
        int row = (t & 3) * 32 + srow;
        const unsigned short* hsrc = (t < 4) ? qh : kh;
        const unsigned short* lsrc = (t < 4) ? ql : kl;
        int base = (t < 4) ? m0 : n0;
        pf[t] = *(const bf16x8*)(((sc8 < 4) ? hsrc : lsrc) +
                                 (size_t)(base + row) * DIM + (kk + 1) * 32 + (sc8 & 3) * 8);
      }
    }
    bf16x8 ah[4], al[4];
    #pragma unroll
    for (int f = 0; f < 4; f++) {
      int ra = wm * 64 + f * 16 + lc;
      ah[f] = *(const bf16x8*)(sA + ra * 128 + ((lr ^ (ra & 7)) << 4));
      al[f] = *(const bf16x8*)(sA + ra * 128 + (((lr + 4) ^ (ra & 7)) << 4));
    }
    // B fragments in halves to cap live VGPRs
    #pragma unroll
    for (int half = 0; half < 2; half++) {
      bf16x8 bh[2], bl[2];
      #pragma unroll
      for (int f2 = 0; f2 < 2; f2++) {
        int rb = wn * 64 + (half * 2 + f2) * 16 + lc;
        bh[f2] = *(const bf16x8*)(sB + rb * 128 + ((lr ^ (rb & 7)) << 4));
        bl[f2] = *(const bf16x8*)(sB + rb * 128 + (((lr + 4) ^ (rb & 7)) << 4));
      }
      #pragma unroll
      for (int fm = 0; fm < 4; fm++)
        #pragma unroll
        for (int f2 = 0; f2 < 2; f2++) {
          int fn = half * 2 + f2;
          acc[fm][fn] = __builtin_amdgcn_mfma_f32_16x16x32_bf16(ah[fm], bh[f2], acc[fm][fn], 0, 0, 0);
          acc[fm][fn] = __builtin_amdgcn_mfma_f32_16x16x32_bf16(ah[fm], bl[f2], acc[fm][fn], 0, 0, 0);
          acc[fm][fn] = __builtin_amdgcn_mfma_f32_16x16x32_bf16(al[fm], bh[f2], acc[fm][fn], 0, 0, 0);
        }
    }
  }
  // epilogue: row argmax (packed u64) + column max (proven r2/r3/r6 form)
  #pragma unroll
  for (int fm = 0; fm < 4; fm++) {
    #pragma unroll
    for (int rg = 0; rg < 4; rg++) {
      unsigned long long p = 0ull;
      #pragma unroll
      for (int fn = 0; fn < 4; fn++) {
        float v = acc[fm][fn][rg];
        unsigned ng = (unsigned)(n0 + wn * 64 + fn * 16 + lc);
        unsigned long long cand =
            ((unsigned long long)ordf(v) << 32) | (unsigned long long)(0xFFFFFFFFu - ng);
        if (cand > p) p = cand;
      }
      #pragma unroll
      for (int o = 1; o < 16; o <<= 1) {
        unsigned long long t2 = __shfl_xor(p, o);
        if (t2 > p) p = t2;
      }
      if (lc == 0)
        atomicMax(rowbest + (m0 + wm * 64 + fm * 16 + lr * 4 + rg), p);
    }
  }
  #pragma unroll
  for (int fn = 0; fn < 4; fn++) {
    float v = -3.4e38f;
    #pragma unroll
    for (int fm = 0; fm < 4; fm++)
      #pragma unroll
      for (int rg = 0; rg < 4; rg++) v = fmaxf(v, acc[fm][fn][rg]);
    v = fmaxf(v, __shfl_xor(v, 16));
    v = fmaxf(v, __shfl_xor(v, 32));
    if (lr == 0) atomicMax(colmax + (n0 + wn * 64 + fn * 16 + lc), ordf(v));
  }
}

// K5: per-query scatter using rowbest/colmax only (no S).
__global__ __launch_bounds__(256) void k_rowscatter(
    const unsigned long long* __restrict__ rowbest, const unsigned* __restrict__ colmax,
    const float* __restrict__ q, float* __restrict__ qu) {
  int i = blockIdx.x, t = threadIdx.x;
  unsigned long long p = rowbest[i];
  int g = (int)(0xFFFFFFFFu - (unsigned)(p & 0xFFFFFFFFull));
  float sv = unordf((unsigned)(p >> 32));
  float w = expf(sv - unordf(colmax[g]));
  atomicAdd(qu + (size_t)g * DIM + t, w * q[(size_t)i * DIM + t]);
}

// K6: mem = l2norm((temp*keys + qu*active) / temp2)
__global__ __launch_bounds__(256) void k_mem(const float* __restrict__ keys,
                                             const float* __restrict__ qu,
                                             const float* __restrict__ sc,
                                             float* __restrict__ memr) {
  int j = blockIdx.x, t = threadIdx.x;
  int last = __float_as_int(sc[0]);
  float count = sc[1], ccl = sc[2];
  unsigned am = __float_as_uint(sc[3]);
  int cls = j >> 9;  // part = 512
  bool inp = (cls == last);
  float temp = inp ? ccl : 1.0f;
  float quv = ((am >> cls) & 1u) ? qu[(size_t)j * DIM + t] : 0.0f;
  float u = temp * keys[(size_t)j * DIM + t] + quv;
  float temp2 = temp + (inp ? count : 0.0f);
  float v = u / temp2;
  float vv = v * v;
  #pragma unroll
  for (int o = 32; o; o >>= 1) vv += __shfl_down(vv, o);
  __shared__ float s[4];
  if ((t & 63) == 0) s[t >> 6] = vv;
  __syncthreads();
  float ss = (s[0] + s[1]) + (s[2] + s[3]);
  memr[(size_t)j * DIM + t] = v / fmaxf(sqrtf(ss), 1e-12f);
}

// K7: G_b = B_b^T B_b (f32 vector compute), emit single bf16 (RN).
__global__ __launch_bounds__(256) void k_gram(const float* __restrict__ memr,
                                              unsigned short* __restrict__ Gb) {
  __shared__ float As[16][64];
  __shared__ float Bs[16][64];
  int b = blockIdx.z;
  int kxc = blockIdx.x * 64;
  int kyr = blockIdx.y * 64;
  const float* Ab = memr + (size_t)b * PRROWS * DIM;
  int tid = threadIdx.x, tx = tid & 15, ty = tid >> 4;
  int lp = tid >> 4;
  int lk = (tid & 15) * 4;
  float acc[4][4] = {};
  for (int p0 = 0; p0 < PRROWS; p0 += 16) {
    float4 av = *(const float4*)(Ab + (size_t)(p0 + lp) * DIM + kyr + lk);
    float4 bv = *(const float4*)(Ab + (size_t)(p0 + lp) * DIM + kxc + lk);
    __syncthreads();
    *(float4*)&As[lp][lk] = av;
    *(float4*)&Bs[lp][lk] = bv;
    __syncthreads();
    #pragma unroll
    for (int p = 0; p < 16; p++) {
      float a[4], c[4];
      *(float4*)&a[0] = *(const float4*)&As[p][ty * 4];
      *(float4*)&c[0] = *(const float4*)&Bs[p][tx * 4];
      #pragma unroll
      for (int r = 0; r < 4; r++)
        #pragma unroll
        for (int s2 = 0; s2 < 4; s2++)
          acc[r][s2] = fmaf(a[r], c[s2], acc[r][s2]);
    }
  }
  #pragma unroll
  for (int r = 0; r < 4; r++)
    #pragma unroll
    for (int s2 = 0; s2 < 4; s2++)
      Gb[(size_t)b * DIM * DIM + (size_t)(kyr + ty * 4 + r) * DIM + kxc + tx * 4 + s2] =
          bf16rn(acc[r][s2]);
}

// K8: out[eb][n][d] = ebT_e[n,:] @ G_b, 1-pass bf16 MFMA, reg-staged LDS
// (verbatim round-3/6 kernel: validated + replay-stable).
__global__ __launch_bounds__(256) void k_read_mfma(
    const unsigned short* __restrict__ ebT, const unsigned short* __restrict__ Gb,
    float* __restrict__ out) {
  __shared__ __align__(16) char smem[32768];
  char* sA = smem;
  char* sB = smem + 16384;
  int tid = threadIdx.x;
  int eb = blockIdx.z;
  const unsigned short* ea = ebT + (size_t)(eb >> 3) * NQE * DIM;
  const unsigned short* gb = Gb + (size_t)(eb & 7) * DIM * DIM;
  int n0 = blockIdx.x * 128, d0 = blockIdx.y * 128;
  int w = tid >> 6, l = tid & 63;
  int wm = w >> 1, wn = w & 1;
  int lr = l >> 4, lc = l & 15;
  f32x4 acc[4][4] = {};
  for (int kk = 0; kk < 4; kk++) {
    __syncthreads();
    #pragma unroll
    for (int t = 0; t < 4; t++) {
      int c = t * 256 + tid;            // 16B chunk id, 0..1023
      int row = c >> 3, cc = c & 7;
      int ldsb = row * 128 + ((cc * 16) ^ ((row & 7) << 4));
      size_t gA = (size_t)(n0 + row) * DIM + kk * 64 + cc * 8;
      size_t gB = (size_t)(d0 + row) * DIM + kk * 64 + cc * 8;
      *(bf16x8*)(sA + ldsb) = *(const bf16x8*)(ea + gA);
      *(bf16x8*)(sB + ldsb) = *(const bf16x8*)(gb + gB);
    }
    __syncthreads();
    #pragma unroll
    for (int st = 0; st < 2; st++) {
      bf16x8 af[4], bf[4];
      #pragma unroll
      for (int f = 0; f < 4; f++) {
        int ra = wm * 64 + f * 16 + lc;
        int ka = (st * 64 + lr * 16) ^ ((ra & 7) << 4);
        af[f] = *(const bf16x8*)(sA + ra * 128 + ka);
        int rb = wn * 64 + f * 16 + lc;
        int kb = (st * 64 + lr * 16) ^ ((rb & 7) << 4);
        bf[f] = *(const bf16x8*)(sB + rb * 128 + kb);
      }
      #pragma unroll
      for (int fm = 0; fm < 4; fm++)
        #pragma unroll
        for (int fn = 0; fn < 4; fn++)
          acc[fm][fn] = __builtin_amdgcn_mfma_f32_16x16x32_bf16(af[fm], bf[fn], acc[fm][fn], 0, 0, 0);
    }
  }
  size_t base = (size_t)eb * NQE * DIM;
  #pragma unroll
  for (int fm = 0; fm < 4; fm++)
    #pragma unroll
    for (int rg = 0; rg < 4; rg++) {
      int n = n0 + wm * 64 + fm * 16 + lr * 4 + rg;
      float* op = out + base + (size_t)n * DIM + d0 + wn * 64 + lc;
      #pragma unroll
      for (int fn = 0; fn < 4; fn++) op[fn * 16] = acc[fm][fn][rg];
    }
}

extern "C" void kernel_launch(void* const* d_in, const int* in_sizes, int n_in,
                              void* d_out, int out_size, void* d_ws, size_t ws_size,
                              hipStream_t stream) {
  const float* query  = (const float*)d_in[0];
  const float* embS   = (const float*)d_in[1];
  const float* embT   = (const float*)d_in[2];
  const float* keys   = (const float*)d_in[3];
  const float* cc     = (const float*)d_in[4];
  const int*   labels = (const int*)d_in[5];
  float* out = (float*)d_out;

  float* q                     = out;
  unsigned short* qh           = (unsigned short*)(out + 2097152);
  unsigned short* ql           = (unsigned short*)(out + 3145728);
  unsigned short* kh           = (unsigned short*)(out + 4194304);
  unsigned short* kl           = (unsigned short*)(out + 4784128);
  float* qu                    = out + 5373952;
  unsigned long long* rowbest  = (unsigned long long*)(out + 6553600);
  unsigned* colmax             = (unsigned*)(out + 6569984);
  float* memr                  = out + 6574592;

  unsigned short* ebT = (unsigned short*)d_ws;                         // 16 MB
  unsigned short* Gb  = (unsigned short*)((char*)d_ws + 16777216);     // 1 MB
  float* sc           = (float*)((char*)d_ws + 17825792);              // 16 B

  k_prep<<<PREP_NBLK, 256, 0, stream>>>(query, q, qh, ql, keys, kh, kl,
                                        embS, embT, ebT, (float4*)qu,
                                        labels, cc, sc);
  k_scoremax<<<dim3(MS / 128, NQRY / 128), 256, 0, stream>>>(qh, ql, kh, kl, rowbest, colmax);
  k_rowscatter<<<NQRY, 256, 0, stream>>>(rowbest, colmax, q, qu);
  k_mem<<<MS, 256, 0, stream>>>(keys, qu, sc, memr);
  k_gram<<<dim3(4, 4, NBLK), 256, 0, stream>>>(memr, Gb);
  k_read_mfma<<<dim3(NQE / 128, DIM / 128, 2 * NBLK), 256, 0, stream>>>(ebT, Gb, out);
}